// Round 1
// baseline (182278.235 us; speedup 1.0000x reference)
//
#include <hip/hip_runtime.h>
#include <cstddef>

namespace {
constexpr int kH = 16;   // hidden
constexpr int kL = 4;    // layers
constexpr int kF = 256;  // input features
constexpr int kA = 16;   // attention dim
constexpr int kG = 48;   // 3*H gates
}

__device__ __forceinline__ float rl(float v, int lane) {
  return __int_as_float(__builtin_amdgcn_readlane(__float_as_int(v), lane));
}
__device__ __forceinline__ float fast_rcp(float x) { return __builtin_amdgcn_rcpf(x); }
__device__ __forceinline__ float sigm(float x) {
  return fast_rcp(1.0f + __expf(-x));
}
__device__ __forceinline__ float tanh_f(float x) {
  // tanh(x) = 1 - 2/(exp(2x)+1); saturates gracefully at +-1
  return 1.0f - 2.0f * fast_rcp(__expf(2.0f * x) + 1.0f);
}

// ---------------- Kernel A: gi0[t][g] = bih0[g] + sum_f batch[t][f]*Wih0[g][f]
__global__ __launch_bounds__(256) void gi0_kernel(
    const float* __restrict__ batch, const float* __restrict__ Wih0,
    const float* __restrict__ bih0, float* __restrict__ gi0, int T) {
  __shared__ __align__(16) float w[kG * kF];
  __shared__ float bsh[kG];
  for (int i = threadIdx.x; i < kG * kF; i += blockDim.x) w[i] = Wih0[i];
  if (threadIdx.x < kG) bsh[threadIdx.x] = bih0[threadIdx.x];
  __syncthreads();
  int t = blockIdx.x * blockDim.x + threadIdx.x;
  if (t >= T) return;
  float acc[kG];
#pragma unroll
  for (int gg = 0; gg < kG; ++gg) acc[gg] = bsh[gg];
  const float* brow = batch + (size_t)t * kF;
  for (int f = 0; f < kF; f += 4) {
    const float4 b4 = *reinterpret_cast<const float4*>(brow + f);
#pragma unroll
    for (int gg = 0; gg < kG; ++gg) {
      const float4 w4 = *reinterpret_cast<const float4*>(&w[gg * kF + f]);
      acc[gg] = fmaf(b4.x, w4.x, acc[gg]);
      acc[gg] = fmaf(b4.y, w4.y, acc[gg]);
      acc[gg] = fmaf(b4.z, w4.z, acc[gg]);
      acc[gg] = fmaf(b4.w, w4.w, acc[gg]);
    }
  }
  float* orow = gi0 + (size_t)t * kG;
#pragma unroll
  for (int gg = 0; gg < kG; gg += 4) {
    *reinterpret_cast<float4*>(orow + gg) =
        make_float4(acc[gg], acc[gg + 1], acc[gg + 2], acc[gg + 3]);
  }
}

// ---------------- Kernel B: the sequential recurrence, one wave of 64 lanes.
// Lane roles:
//   GRU:   lanes 0..47 compute gates (0-15 r, 16-31 z, 32-47 n) of current layer.
//   State: hs (one VGPR): lane l*16+k holds h[l][k] for all 4 layers.
//   Attn:  lane = i*16+a  (head i, attention unit a).
__global__ __launch_bounds__(64) void seq_kernel(
    const float* __restrict__ Whh0, const float* __restrict__ bhh0,
    const float* __restrict__ Wih, const float* __restrict__ Whh,
    const float* __restrict__ bih, const float* __restrict__ bhh,
    const float* __restrict__ aW, const float* __restrict__ ab,
    const float* __restrict__ av, const float* __restrict__ avb,
    const float* __restrict__ gi0, float* __restrict__ topout, int T) {
  const int lane = threadIdx.x & 63;
  const int g = lane < kG ? lane : (kG - 1);  // clamp: lanes 48..63 duplicate row 47

  // --- weight preload into registers (per-lane rows) ---
  float whh0r[kH], whhr[3][kH], wihr[3][kH];
#pragma unroll
  for (int k = 0; k < kH; ++k) whh0r[k] = Whh0[g * kH + k];
#pragma unroll
  for (int l = 0; l < 3; ++l) {
#pragma unroll
    for (int k = 0; k < kH; ++k) {
      whhr[l][k] = Whh[(l * kG + g) * kH + k];
      wihr[l][k] = Wih[(l * kG + g) * kH + k];
    }
  }
  const float bhh0v = bhh0[g];
  float bihv[3], bhhv[3];
#pragma unroll
  for (int l = 0; l < 3; ++l) {
    bihv[l] = bih[l * kG + g];
    bhhv[l] = bhh[l * kG + g];
  }
  const int ai = lane >> 4;   // attention head
  const int aa = lane & 15;   // attention unit
  float aWr[kH];
#pragma unroll
  for (int k = 0; k < kH; ++k) aWr[k] = aW[(ai * kH + k) * kA + aa];
  const float abr = ab[ai * kA + aa];
  const float avr = av[ai * kA + aa];
  const float avbr = avb[ai];

  const int i15 = lane & 15;

  float hs = 0.0f;  // packed hidden state, all layers
  // gi0 prefetch pipeline (distance 2)
  float giA = gi0[0 * kG + g];
  float giB = gi0[1 * kG + g];

  for (int t = 0; t < T; ++t) {
    const float gicur = giA;
    giA = giB;
    {
      const int tn = (t + 2 < T) ? (t + 2) : (T - 1);
      giB = gi0[(size_t)tn * kG + g];
    }

    float xv[kL];        // new GRU outputs (valid in lanes 0..15)
    float hnl[kL][kH];   // uniform broadcast copies (readlane -> sgpr)

#pragma unroll
    for (int l = 0; l < kL; ++l) {
      // gh = h[l] @ Whh[l].T + bhh[l]
      float acc_h = (l == 0) ? bhh0v : bhhv[l - 1];
#pragma unroll
      for (int k = 0; k < kH; ++k) {
        const float hv = rl(hs, l * kH + k);
        acc_h = fmaf(hv, (l == 0) ? whh0r[k] : whhr[l - 1][k], acc_h);
      }
      // gi = inp @ Wih[l].T + bih[l]   (layer 0: precomputed)
      float acc_i;
      if (l == 0) {
        acc_i = gicur;
      } else {
        acc_i = bihv[l - 1];
#pragma unroll
        for (int k = 0; k < kH; ++k)
          acc_i = fmaf(hnl[l - 1][k], wihr[l - 1][k], acc_i);
      }
      const float hold = __shfl(hs, l * kH + i15, 64);  // old h per-lane (lanes 0..15)
      const float sg = sigm(acc_i + acc_h);             // r (0-15) / z (16-31)
      const float rv = __shfl(sg, i15, 64);             // r_j delivered to lane 32+j
      const float nt = tanh_f(fmaf(rv, acc_h, acc_i));  // n = tanh(inn + r*hn)
      const float zv = __shfl(sg, i15 + 16, 64);        // z_j to lane j
      const float nv = __shfl(nt, i15 + 32, 64);        // n_j to lane j
      const float hnew = fmaf(zv, hold - nv, nv);       // (1-z)n + z*h
      xv[l] = hnew;
#pragma unroll
      for (int k = 0; k < kH; ++k) hnl[l][k] = rl(hnew, k);
    }

    // replicate each layer's output across all four 16-lane groups
    float xr[kL];
#pragma unroll
    for (int j = 0; j < kL; ++j) xr[j] = __shfl(xv[j], i15, 64);

    // attention scores s[i][j] (head i = lane group, all heads in parallel)
    float sc[kL];
#pragma unroll
    for (int j = 0; j < kL; ++j) {
      float d = abr;
#pragma unroll
      for (int k = 0; k < kH; ++k) d = fmaf(hnl[j][k], aWr[k], d);
      d = tanh_f(d);
      float p = d * avr;
      p += __shfl_xor(p, 1, 64);
      p += __shfl_xor(p, 2, 64);
      p += __shfl_xor(p, 4, 64);
      p += __shfl_xor(p, 8, 64);
      sc[j] = p + avbr;
    }
    // softmax over valid j >= head index
    float m = -1e30f;
#pragma unroll
    for (int j = 0; j < kL; ++j) {
      const float sj = (j >= ai) ? sc[j] : -1e30f;
      m = fmaxf(m, sj);
    }
    float ev[kL];
    float den = 0.0f;
#pragma unroll
    for (int j = 0; j < kL; ++j) {
      ev[j] = (j >= ai) ? __expf(sc[j] - m) : 0.0f;
      den += ev[j];
    }
    const float rden = fast_rcp(den);
    float hnext = 0.0f;
#pragma unroll
    for (int j = 0; j < kL; ++j) hnext = fmaf(ev[j] * rden, xr[j], hnext);
    hs = hnext;

    // persist top layer state (head 3 output) for the FC epilogue
    if (lane >= 48) topout[(size_t)t * kH + (lane - 48)] = hs;
  }
}

// ---------------- Kernel C: out[t] = fc2( relu( fc1( top[t] ) ) )
__global__ __launch_bounds__(256) void head_kernel(
    const float* __restrict__ top, const float* __restrict__ fc1W,
    const float* __restrict__ fc1b, const float* __restrict__ fc2W,
    const float* __restrict__ fc2b, float* __restrict__ out, int T) {
  __shared__ __align__(16) float w1[32 * kH];
  __shared__ float b1[32], w2[32];
  for (int i = threadIdx.x; i < 32 * kH; i += blockDim.x) w1[i] = fc1W[i];
  if (threadIdx.x < 32) {
    b1[threadIdx.x] = fc1b[threadIdx.x];
    w2[threadIdx.x] = fc2W[threadIdx.x];
  }
  __syncthreads();
  int t = blockIdx.x * blockDim.x + threadIdx.x;
  if (t >= T) return;
  const float* hrow = top + (size_t)t * kH;
  float hv[kH];
#pragma unroll
  for (int k = 0; k < kH; k += 4) {
    const float4 h4 = *reinterpret_cast<const float4*>(hrow + k);
    hv[k] = h4.x; hv[k + 1] = h4.y; hv[k + 2] = h4.z; hv[k + 3] = h4.w;
  }
  float o = fc2b[0];
#pragma unroll
  for (int mth = 0; mth < 32; ++mth) {
    float a = b1[mth];
#pragma unroll
    for (int k = 0; k < kH; ++k) a = fmaf(hv[k], w1[mth * kH + k], a);
    a = fmaxf(a, 0.0f);
    o = fmaf(a, w2[mth], o);
  }
  out[t] = o;
}

extern "C" void kernel_launch(void* const* d_in, const int* in_sizes, int n_in,
                              void* d_out, int out_size, void* d_ws, size_t ws_size,
                              hipStream_t stream) {
  const float* batch = (const float*)d_in[0];
  const float* Wih0  = (const float*)d_in[1];
  const float* Whh0  = (const float*)d_in[2];
  const float* bih0  = (const float*)d_in[3];
  const float* bhh0  = (const float*)d_in[4];
  const float* Wih   = (const float*)d_in[5];
  const float* Whh   = (const float*)d_in[6];
  const float* bih   = (const float*)d_in[7];
  const float* bhh   = (const float*)d_in[8];
  const float* aW    = (const float*)d_in[9];
  const float* ab    = (const float*)d_in[10];
  const float* av    = (const float*)d_in[11];
  const float* avb   = (const float*)d_in[12];
  const float* fc1W  = (const float*)d_in[13];
  const float* fc1b  = (const float*)d_in[14];
  const float* fc2W  = (const float*)d_in[15];
  const float* fc2b  = (const float*)d_in[16];
  float* out = (float*)d_out;

  const int T = in_sizes[0] / kF;  // 131072

  // workspace layout: gi0 [T*48 f32] | top [T*16 f32]  => 32 MB total
  float* gi0 = (float*)d_ws;
  float* top = gi0 + (size_t)T * kG;

  const int blocks = (T + 255) / 256;
  gi0_kernel<<<blocks, 256, 0, stream>>>(batch, Wih0, bih0, gi0, T);
  seq_kernel<<<1, 64, 0, stream>>>(Whh0, bhh0, Wih, Whh, bih, bhh,
                                   aW, ab, av, avb, gi0, top, T);
  head_kernel<<<blocks, 256, 0, stream>>>(top, fc1W, fc1b, fc2W, fc2b, out, T);
}

// Round 2
// 155711.304 us; speedup vs baseline: 1.1706x; 1.1706x over previous
//
#include <hip/hip_runtime.h>
#include <cstddef>

namespace {
constexpr int kH = 16;   // hidden
constexpr int kL = 4;    // layers
constexpr int kF = 256;  // input features
constexpr int kA = 16;   // attention dim
constexpr int kG = 48;   // 3*H gates
}

__device__ __forceinline__ float rl(float v, int lane) {
  return __int_as_float(__builtin_amdgcn_readlane(__float_as_int(v), lane));
}
template <int PAT>
__device__ __forceinline__ float swz(float v) {
  return __int_as_float(__builtin_amdgcn_ds_swizzle(__float_as_int(v), PAT));
}
// add value rotated by N within each 16-lane row (DPP row_ror)
template <int CTRL>
__device__ __forceinline__ float ror_add(float x) {
  int r = __builtin_amdgcn_update_dpp(0, __float_as_int(x), CTRL, 0xF, 0xF, false);
  return x + __int_as_float(r);
}
__device__ __forceinline__ float row_sum16(float x) {
  x = ror_add<0x128>(x);  // ror 8
  x = ror_add<0x124>(x);  // ror 4
  x = ror_add<0x122>(x);  // ror 2
  x = ror_add<0x121>(x);  // ror 1
  return x;
}
__device__ __forceinline__ float fast_rcp(float x) { return __builtin_amdgcn_rcpf(x); }
constexpr float kL2E = 1.4426950408889634f;
__device__ __forceinline__ float sigm(float x) {
  return fast_rcp(1.0f + __builtin_amdgcn_exp2f(-kL2E * x));
}
__device__ __forceinline__ float tanh_f(float x) {
  return 1.0f - 2.0f * fast_rcp(1.0f + __builtin_amdgcn_exp2f((2.0f * kL2E) * x));
}

// ---------------- Kernel A: gi0[t][g] = bih0[g] + sum_f batch[t][f]*Wih0[g][f]
__global__ __launch_bounds__(256) void gi0_kernel(
    const float* __restrict__ batch, const float* __restrict__ Wih0,
    const float* __restrict__ bih0, float* __restrict__ gi0, int T) {
  __shared__ __align__(16) float w[kG * kF];
  __shared__ float bsh[kG];
  for (int i = threadIdx.x; i < kG * kF; i += blockDim.x) w[i] = Wih0[i];
  if (threadIdx.x < kG) bsh[threadIdx.x] = bih0[threadIdx.x];
  __syncthreads();
  int t = blockIdx.x * blockDim.x + threadIdx.x;
  if (t >= T) return;
  float acc[kG];
#pragma unroll
  for (int gg = 0; gg < kG; ++gg) acc[gg] = bsh[gg];
  const float* brow = batch + (size_t)t * kF;
  for (int f = 0; f < kF; f += 4) {
    const float4 b4 = *reinterpret_cast<const float4*>(brow + f);
#pragma unroll
    for (int gg = 0; gg < kG; ++gg) {
      const float4 w4 = *reinterpret_cast<const float4*>(&w[gg * kF + f]);
      acc[gg] = fmaf(b4.x, w4.x, acc[gg]);
      acc[gg] = fmaf(b4.y, w4.y, acc[gg]);
      acc[gg] = fmaf(b4.z, w4.z, acc[gg]);
      acc[gg] = fmaf(b4.w, w4.w, acc[gg]);
    }
  }
  float* orow = gi0 + (size_t)t * kG;
#pragma unroll
  for (int gg = 0; gg < kG; gg += 4) {
    *reinterpret_cast<float4*>(orow + gg) =
        make_float4(acc[gg], acc[gg + 1], acc[gg + 2], acc[gg + 3]);
  }
}

// ---------------- Kernel B: the sequential recurrence, one wave of 64 lanes.
// Gate rows: row0 (lanes 0-15) = r, row1 (16-31) = n, rows2,3 = z (dup).
// hnew computed in row1; attention head i = row i; state hs: lane 16*l+k = h[l][k].
__global__ __launch_bounds__(64, 1) void seq_kernel(
    const float* __restrict__ Whh0, const float* __restrict__ bhh0,
    const float* __restrict__ Wih, const float* __restrict__ Whh,
    const float* __restrict__ bih, const float* __restrict__ bhh,
    const float* __restrict__ aW, const float* __restrict__ ab,
    const float* __restrict__ av, const float* __restrict__ avb,
    const float* __restrict__ gi0, float* __restrict__ topout, int T) {
  const int lane = threadIdx.x & 63;
  const int grp = lane >> 4;
  const int k15 = lane & 15;
  // weight row in gate space: r rows 0-15, z rows 16-31, n rows 32-47
  const int wrow = (grp == 0) ? k15 : (grp == 1 ? 32 + k15 : 16 + k15);

  // --- per-lane weight rows in VGPRs ---
  float whhr[kL][kH];  // layer 0..3 hidden-hidden row
  float wihr[3][kH];   // layers 1..3 input-hidden row
#pragma unroll
  for (int k = 0; k < kH; ++k) whhr[0][k] = Whh0[wrow * kH + k];
#pragma unroll
  for (int l = 1; l < kL; ++l) {
#pragma unroll
    for (int k = 0; k < kH; ++k) {
      whhr[l][k] = Whh[((l - 1) * kG + wrow) * kH + k];
      wihr[l - 1][k] = Wih[((l - 1) * kG + wrow) * kH + k];
    }
  }
  float bhhv[kL], bihv[3];
  bhhv[0] = bhh0[wrow];
#pragma unroll
  for (int l = 1; l < kL; ++l) {
    bhhv[l] = bhh[(l - 1) * kG + wrow];
    bihv[l - 1] = bih[(l - 1) * kG + wrow];
  }
  // attention params: head grp, unit k15
  float aWr[kH];
#pragma unroll
  for (int k = 0; k < kH; ++k) aWr[k] = aW[(grp * kH + k) * kA + k15];
  const float abr = ab[grp * kA + k15];
  const float avr = av[grp * kA + k15];
  const float avbr = avb[grp];

  const int s16 = 16 + k15, s32 = 32 + k15, s48 = 48 + k15;

  float hs = 0.0f;
  const float* gptr = gi0 + wrow;
  float g0 = gptr[0 * kG], g1 = gptr[1 * kG], g2 = gptr[2 * kG];

  for (int t = 0; t < T; ++t) {
    const float gcur = g0;
    g0 = g1;
    g1 = g2;
    {
      int tn = t + 3;
      tn = tn < T ? tn : T - 1;
      g2 = gptr[(size_t)tn * kG];
    }

    // gh for all layers (depends only on hs -> off critical path)
    float gh[kL];
#pragma unroll
    for (int l = 0; l < kL; ++l) {
      float a0 = bhhv[l], a1 = 0.f, a2 = 0.f, a3 = 0.f;
#pragma unroll
      for (int k = 0; k < kH; k += 4) {
        a0 = fmaf(rl(hs, l * kH + k + 0), whhr[l][k + 0], a0);
        a1 = fmaf(rl(hs, l * kH + k + 1), whhr[l][k + 1], a1);
        a2 = fmaf(rl(hs, l * kH + k + 2), whhr[l][k + 2], a2);
        a3 = fmaf(rl(hs, l * kH + k + 3), whhr[l][k + 3], a3);
      }
      gh[l] = (a0 + a1) + (a2 + a3);
    }
    // old-h per row1 lane, per layer (off critical path)
    const float hold0 = swz<0x000F>(hs);     // lane 16+k <- hs[k]
    const float hold1 = hs;                  // lane 16+k holds h[1][k]
    const float hold2 = __shfl(hs, s32, 64);
    const float hold3 = __shfl(hs, s48, 64);

    float hn[kL];     // GRU outputs, valid in row1 (lanes 16-31)
    float sc[kL];     // attention scores (uniform per row)
    float xs[kL][kH]; // broadcast scalars of x_l

#pragma unroll
    for (int l = 0; l < kL; ++l) {
      // gi chain (layer 0 precomputed)
      float acc_i;
      if (l == 0) {
        acc_i = gcur;
      } else {
        float a0 = bihv[l - 1], a1 = 0.f, a2 = 0.f, a3 = 0.f;
#pragma unroll
        for (int k = 0; k < kH; k += 4) {
          a0 = fmaf(xs[l - 1][k + 0], wihr[l - 1][k + 0], a0);
          a1 = fmaf(xs[l - 1][k + 1], wihr[l - 1][k + 1], a1);
          a2 = fmaf(xs[l - 1][k + 2], wihr[l - 1][k + 2], a2);
          a3 = fmaf(xs[l - 1][k + 3], wihr[l - 1][k + 3], a3);
        }
        acc_i = (a0 + a1) + (a2 + a3);
      }
      const float pre = acc_i + gh[l];
      const float sg = sigm(pre);             // r in row0, z in rows 2,3
      const float rv = swz<0x000F>(sg);       // r_k -> lane 16+k
      const float zv = __shfl(sg, s32, 64);   // z_k -> lane 16+k (parallel path)
      const float nt = tanh_f(fmaf(rv, gh[l], acc_i));  // n in row1
      const float hold = (l == 0) ? hold0 : (l == 1) ? hold1
                       : (l == 2) ? hold2 : hold3;
      const float hnew = fmaf(zv, hold - nt, nt);  // valid row1
      hn[l] = hnew;
#pragma unroll
      for (int k = 0; k < kH; ++k) xs[l][k] = rl(hnew, kH + k);

      // attention score for j = l (only needs xs[l]) — keeps live ranges short
      {
        float a0 = abr, a1 = 0.f, a2 = 0.f, a3 = 0.f;
#pragma unroll
        for (int k = 0; k < kH; k += 4) {
          a0 = fmaf(xs[l][k + 0], aWr[k + 0], a0);
          a1 = fmaf(xs[l][k + 1], aWr[k + 1], a1);
          a2 = fmaf(xs[l][k + 2], aWr[k + 2], a2);
          a3 = fmaf(xs[l][k + 3], aWr[k + 3], a3);
        }
        const float d = tanh_f((a0 + a1) + (a2 + a3));
        sc[l] = row_sum16(d * avr) + avbr;
      }
    }

    // masked softmax over j >= grp (uniform within each row)
    const float s0 = (grp == 0) ? sc[0] : -1e30f;
    const float s1 = (grp <= 1) ? sc[1] : -1e30f;
    const float s2 = (grp <= 2) ? sc[2] : -1e30f;
    const float s3 = sc[3];
    const float m = fmaxf(fmaxf(s0, s1), fmaxf(s2, s3));
    const float e0 = __builtin_amdgcn_exp2f((s0 - m) * kL2E);
    const float e1 = __builtin_amdgcn_exp2f((s1 - m) * kL2E);
    const float e2 = __builtin_amdgcn_exp2f((s2 - m) * kL2E);
    const float e3 = __builtin_amdgcn_exp2f((s3 - m) * kL2E);
    const float rden = fast_rcp((e0 + e1) + (e2 + e3));
    // x_j[a] delivered to lane (i, a) from row1 of hn[j]
    const float x0 = __shfl(hn[0], s16, 64);
    const float x1 = __shfl(hn[1], s16, 64);
    const float x2 = __shfl(hn[2], s16, 64);
    const float x3 = __shfl(hn[3], s16, 64);
    float num = e0 * x0;
    num = fmaf(e1, x1, num);
    num = fmaf(e2, x2, num);
    num = fmaf(e3, x3, num);
    hs = num * rden;

    if (lane >= 48) topout[(size_t)t * kH + k15] = hs;  // head 3 output
  }
}

// ---------------- Kernel C: out[t] = fc2( relu( fc1( top[t] ) ) )
__global__ __launch_bounds__(256) void head_kernel(
    const float* __restrict__ top, const float* __restrict__ fc1W,
    const float* __restrict__ fc1b, const float* __restrict__ fc2W,
    const float* __restrict__ fc2b, float* __restrict__ out, int T) {
  __shared__ __align__(16) float w1[32 * kH];
  __shared__ float b1[32], w2[32];
  for (int i = threadIdx.x; i < 32 * kH; i += blockDim.x) w1[i] = fc1W[i];
  if (threadIdx.x < 32) {
    b1[threadIdx.x] = fc1b[threadIdx.x];
    w2[threadIdx.x] = fc2W[threadIdx.x];
  }
  __syncthreads();
  int t = blockIdx.x * blockDim.x + threadIdx.x;
  if (t >= T) return;
  const float* hrow = top + (size_t)t * kH;
  float hv[kH];
#pragma unroll
  for (int k = 0; k < kH; k += 4) {
    const float4 h4 = *reinterpret_cast<const float4*>(hrow + k);
    hv[k] = h4.x; hv[k + 1] = h4.y; hv[k + 2] = h4.z; hv[k + 3] = h4.w;
  }
  float o = fc2b[0];
#pragma unroll
  for (int mth = 0; mth < 32; ++mth) {
    float a = b1[mth];
#pragma unroll
    for (int k = 0; k < kH; ++k) a = fmaf(hv[k], w1[mth * kH + k], a);
    a = fmaxf(a, 0.0f);
    o = fmaf(a, w2[mth], o);
  }
  out[t] = o;
}

extern "C" void kernel_launch(void* const* d_in, const int* in_sizes, int n_in,
                              void* d_out, int out_size, void* d_ws, size_t ws_size,
                              hipStream_t stream) {
  const float* batch = (const float*)d_in[0];
  const float* Wih0  = (const float*)d_in[1];
  const float* Whh0  = (const float*)d_in[2];
  const float* bih0  = (const float*)d_in[3];
  const float* bhh0  = (const float*)d_in[4];
  const float* Wih   = (const float*)d_in[5];
  const float* Whh   = (const float*)d_in[6];
  const float* bih   = (const float*)d_in[7];
  const float* bhh   = (const float*)d_in[8];
  const float* aW    = (const float*)d_in[9];
  const float* ab    = (const float*)d_in[10];
  const float* av    = (const float*)d_in[11];
  const float* avb   = (const float*)d_in[12];
  const float* fc1W  = (const float*)d_in[13];
  const float* fc1b  = (const float*)d_in[14];
  const float* fc2W  = (const float*)d_in[15];
  const float* fc2b  = (const float*)d_in[16];
  float* out = (float*)d_out;

  const int T = in_sizes[0] / kF;  // 131072

  // workspace layout: gi0 [T*48 f32] | top [T*16 f32]
  float* gi0 = (float*)d_ws;
  float* top = gi0 + (size_t)T * kG;

  const int blocks = (T + 255) / 256;
  gi0_kernel<<<blocks, 256, 0, stream>>>(batch, Wih0, bih0, gi0, T);
  seq_kernel<<<1, 64, 0, stream>>>(Whh0, bhh0, Wih, Whh, bih, bhh,
                                   aW, ab, av, avb, gi0, top, T);
  head_kernel<<<blocks, 256, 0, stream>>>(top, fc1W, fc1b, fc2W, fc2b, out, T);
}

// Round 3
// 155593.091 us; speedup vs baseline: 1.1715x; 1.0008x over previous
//
#include <hip/hip_runtime.h>
#include <cstddef>

namespace {
constexpr int kH = 16;   // hidden
constexpr int kL = 4;    // layers
constexpr int kF = 256;  // input features
constexpr int kA = 16;   // attention dim
constexpr int kG = 48;   // 3*H gates
}

// Pin a value into a VGPR: opaque to the optimizer, so it cannot be
// rematerialized by re-loading from memory inside the loop.
#define PIN(x) asm volatile("" : "+v"(x))

__device__ __forceinline__ float rl(float v, int lane) {
  return __int_as_float(__builtin_amdgcn_readlane(__float_as_int(v), lane));
}
template <int PAT>
__device__ __forceinline__ float swz(float v) {
  return __int_as_float(__builtin_amdgcn_ds_swizzle(__float_as_int(v), PAT));
}
// add value rotated by N within each 16-lane row (DPP row_ror)
template <int CTRL>
__device__ __forceinline__ float ror_add(float x) {
  int r = __builtin_amdgcn_update_dpp(0, __float_as_int(x), CTRL, 0xF, 0xF, false);
  return x + __int_as_float(r);
}
__device__ __forceinline__ float row_sum16(float x) {
  x = ror_add<0x128>(x);  // ror 8
  x = ror_add<0x124>(x);  // ror 4
  x = ror_add<0x122>(x);  // ror 2
  x = ror_add<0x121>(x);  // ror 1
  return x;
}
__device__ __forceinline__ float fast_rcp(float x) { return __builtin_amdgcn_rcpf(x); }
constexpr float kL2E = 1.4426950408889634f;
__device__ __forceinline__ float sigm(float x) {
  return fast_rcp(1.0f + __builtin_amdgcn_exp2f(-kL2E * x));
}
__device__ __forceinline__ float tanh_f(float x) {
  return 1.0f - 2.0f * fast_rcp(1.0f + __builtin_amdgcn_exp2f((2.0f * kL2E) * x));
}

// ---------------- Kernel A: gi0[t][g] = bih0[g] + sum_f batch[t][f]*Wih0[g][f]
__global__ __launch_bounds__(256) void gi0_kernel(
    const float* __restrict__ batch, const float* __restrict__ Wih0,
    const float* __restrict__ bih0, float* __restrict__ gi0, int T) {
  __shared__ __align__(16) float w[kG * kF];
  __shared__ float bsh[kG];
  for (int i = threadIdx.x; i < kG * kF; i += blockDim.x) w[i] = Wih0[i];
  if (threadIdx.x < kG) bsh[threadIdx.x] = bih0[threadIdx.x];
  __syncthreads();
  int t = blockIdx.x * blockDim.x + threadIdx.x;
  if (t >= T) return;
  float acc[kG];
#pragma unroll
  for (int gg = 0; gg < kG; ++gg) acc[gg] = bsh[gg];
  const float* brow = batch + (size_t)t * kF;
  for (int f = 0; f < kF; f += 4) {
    const float4 b4 = *reinterpret_cast<const float4*>(brow + f);
#pragma unroll
    for (int gg = 0; gg < kG; ++gg) {
      const float4 w4 = *reinterpret_cast<const float4*>(&w[gg * kF + f]);
      acc[gg] = fmaf(b4.x, w4.x, acc[gg]);
      acc[gg] = fmaf(b4.y, w4.y, acc[gg]);
      acc[gg] = fmaf(b4.z, w4.z, acc[gg]);
      acc[gg] = fmaf(b4.w, w4.w, acc[gg]);
    }
  }
  float* orow = gi0 + (size_t)t * kG;
#pragma unroll
  for (int gg = 0; gg < kG; gg += 4) {
    *reinterpret_cast<float4*>(orow + gg) =
        make_float4(acc[gg], acc[gg + 1], acc[gg + 2], acc[gg + 3]);
  }
}

// ---------------- Kernel B: the sequential recurrence, one wave of 64 lanes.
// Gate rows: row0 (lanes 0-15) = r, row1 (16-31) = n, rows2,3 = z (dup).
// hnew computed in row1; attention head i = row i; state hs: lane 16*l+k = h[l][k].
__global__ __launch_bounds__(64, 1) void seq_kernel(
    const float* __restrict__ Whh0, const float* __restrict__ bhh0,
    const float* __restrict__ Wih, const float* __restrict__ Whh,
    const float* __restrict__ bih, const float* __restrict__ bhh,
    const float* __restrict__ aW, const float* __restrict__ ab,
    const float* __restrict__ av, const float* __restrict__ avb,
    const float* __restrict__ gi0, float* __restrict__ topout, int T) {
  const int lane = threadIdx.x & 63;
  const int grp = lane >> 4;
  const int k15 = lane & 15;
  // weight row in gate space: r rows 0-15, z rows 16-31, n rows 32-47
  const int wrow = (grp == 0) ? k15 : (grp == 1 ? 32 + k15 : 16 + k15);

  // --- per-lane weight rows in VGPRs (pinned: cannot be re-loaded in-loop) ---
  float whhr[kL][kH];  // layer 0..3 hidden-hidden row
  float wihr[3][kH];   // layers 1..3 input-hidden row
#pragma unroll
  for (int k = 0; k < kH; ++k) whhr[0][k] = Whh0[wrow * kH + k];
#pragma unroll
  for (int l = 1; l < kL; ++l) {
#pragma unroll
    for (int k = 0; k < kH; ++k) {
      whhr[l][k] = Whh[((l - 1) * kG + wrow) * kH + k];
      wihr[l - 1][k] = Wih[((l - 1) * kG + wrow) * kH + k];
    }
  }
  float bhhv[kL], bihv[3];
  bhhv[0] = bhh0[wrow];
#pragma unroll
  for (int l = 1; l < kL; ++l) {
    bhhv[l] = bhh[(l - 1) * kG + wrow];
    bihv[l - 1] = bih[(l - 1) * kG + wrow];
  }
  // attention params: head grp, unit k15
  float aWr[kH];
#pragma unroll
  for (int k = 0; k < kH; ++k) aWr[k] = aW[(grp * kH + k) * kA + k15];
  float abr = ab[grp * kA + k15];
  float avr = av[grp * kA + k15];
  float avbr = avb[grp];

  // pin everything
#pragma unroll
  for (int l = 0; l < kL; ++l) {
#pragma unroll
    for (int k = 0; k < kH; ++k) PIN(whhr[l][k]);
    PIN(bhhv[l]);
  }
#pragma unroll
  for (int l = 0; l < 3; ++l) {
#pragma unroll
    for (int k = 0; k < kH; ++k) PIN(wihr[l][k]);
    PIN(bihv[l]);
  }
#pragma unroll
  for (int k = 0; k < kH; ++k) PIN(aWr[k]);
  PIN(abr); PIN(avr); PIN(avbr);

  const int s16 = 16 + k15, s32 = 32 + k15, s48 = 48 + k15;

  float hs = 0.0f;
  const float* gptr = gi0 + wrow;
  // prefetch pipeline, distance 4 (keeps >=3 loads in flight)
  float g0 = gptr[0 * kG], g1 = gptr[1 * kG], g2 = gptr[2 * kG], g3 = gptr[3 * kG];

  for (int t = 0; t < T; ++t) {
    const float gcur = g0;
    g0 = g1;
    g1 = g2;
    g2 = g3;
    {
      int tn = t + 4;
      tn = tn < T ? tn : T - 1;
      g3 = gptr[(size_t)tn * kG];
    }

    // gh for all layers (depends only on hs -> off critical path)
    float gh[kL];
#pragma unroll
    for (int l = 0; l < kL; ++l) {
      float a0 = bhhv[l], a1 = 0.f, a2 = 0.f, a3 = 0.f;
#pragma unroll
      for (int k = 0; k < kH; k += 4) {
        a0 = fmaf(rl(hs, l * kH + k + 0), whhr[l][k + 0], a0);
        a1 = fmaf(rl(hs, l * kH + k + 1), whhr[l][k + 1], a1);
        a2 = fmaf(rl(hs, l * kH + k + 2), whhr[l][k + 2], a2);
        a3 = fmaf(rl(hs, l * kH + k + 3), whhr[l][k + 3], a3);
      }
      gh[l] = (a0 + a1) + (a2 + a3);
    }
    // old-h per row1 lane, per layer (off critical path)
    const float hold0 = swz<0x000F>(hs);     // lane 16+k <- hs[k]
    const float hold1 = hs;                  // lane 16+k holds h[1][k]
    const float hold2 = __shfl(hs, s32, 64);
    const float hold3 = __shfl(hs, s48, 64);

    float hn[kL];     // GRU outputs, valid in row1 (lanes 16-31)
    float sc[kL];     // attention scores (uniform per row)
    float xs[kL][kH]; // broadcast scalars of x_l

#pragma unroll
    for (int l = 0; l < kL; ++l) {
      // gi chain (layer 0 precomputed)
      float acc_i;
      if (l == 0) {
        acc_i = gcur;
      } else {
        float a0 = bihv[l - 1], a1 = 0.f, a2 = 0.f, a3 = 0.f;
#pragma unroll
        for (int k = 0; k < kH; k += 4) {
          a0 = fmaf(xs[l - 1][k + 0], wihr[l - 1][k + 0], a0);
          a1 = fmaf(xs[l - 1][k + 1], wihr[l - 1][k + 1], a1);
          a2 = fmaf(xs[l - 1][k + 2], wihr[l - 1][k + 2], a2);
          a3 = fmaf(xs[l - 1][k + 3], wihr[l - 1][k + 3], a3);
        }
        acc_i = (a0 + a1) + (a2 + a3);
      }
      const float pre = acc_i + gh[l];
      const float sg = sigm(pre);             // r in row0, z in rows 2,3
      const float rv = swz<0x000F>(sg);       // r_k -> lane 16+k
      const float zv = __shfl(sg, s32, 64);   // z_k -> lane 16+k (parallel path)
      const float nt = tanh_f(fmaf(rv, gh[l], acc_i));  // n in row1
      const float hold = (l == 0) ? hold0 : (l == 1) ? hold1
                       : (l == 2) ? hold2 : hold3;
      const float hnew = fmaf(zv, hold - nt, nt);  // valid row1
      hn[l] = hnew;
#pragma unroll
      for (int k = 0; k < kH; ++k) xs[l][k] = rl(hnew, kH + k);

      // attention score for j = l (only needs xs[l]) — keeps live ranges short
      {
        float a0 = abr, a1 = 0.f, a2 = 0.f, a3 = 0.f;
#pragma unroll
        for (int k = 0; k < kH; k += 4) {
          a0 = fmaf(xs[l][k + 0], aWr[k + 0], a0);
          a1 = fmaf(xs[l][k + 1], aWr[k + 1], a1);
          a2 = fmaf(xs[l][k + 2], aWr[k + 2], a2);
          a3 = fmaf(xs[l][k + 3], aWr[k + 3], a3);
        }
        const float d = tanh_f((a0 + a1) + (a2 + a3));
        sc[l] = row_sum16(d * avr) + avbr;
      }
    }

    // masked softmax over j >= grp (uniform within each row)
    const float s0 = (grp == 0) ? sc[0] : -1e30f;
    const float s1 = (grp <= 1) ? sc[1] : -1e30f;
    const float s2 = (grp <= 2) ? sc[2] : -1e30f;
    const float s3 = sc[3];
    const float m = fmaxf(fmaxf(s0, s1), fmaxf(s2, s3));
    const float e0 = __builtin_amdgcn_exp2f((s0 - m) * kL2E);
    const float e1 = __builtin_amdgcn_exp2f((s1 - m) * kL2E);
    const float e2 = __builtin_amdgcn_exp2f((s2 - m) * kL2E);
    const float e3 = __builtin_amdgcn_exp2f((s3 - m) * kL2E);
    const float rden = fast_rcp((e0 + e1) + (e2 + e3));
    // x_j[a] delivered to lane (i, a) from row1 of hn[j]
    const float x0 = __shfl(hn[0], s16, 64);
    const float x1 = __shfl(hn[1], s16, 64);
    const float x2 = __shfl(hn[2], s16, 64);
    const float x3 = __shfl(hn[3], s16, 64);
    float num = e0 * x0;
    num = fmaf(e1, x1, num);
    num = fmaf(e2, x2, num);
    num = fmaf(e3, x3, num);
    hs = num * rden;

    if (lane >= 48) topout[(size_t)t * kH + k15] = hs;  // head 3 output
  }
}

// ---------------- Kernel C: out[t] = fc2( relu( fc1( top[t] ) ) )
__global__ __launch_bounds__(256) void head_kernel(
    const float* __restrict__ top, const float* __restrict__ fc1W,
    const float* __restrict__ fc1b, const float* __restrict__ fc2W,
    const float* __restrict__ fc2b, float* __restrict__ out, int T) {
  __shared__ __align__(16) float w1[32 * kH];
  __shared__ float b1[32], w2[32];
  for (int i = threadIdx.x; i < 32 * kH; i += blockDim.x) w1[i] = fc1W[i];
  if (threadIdx.x < 32) {
    b1[threadIdx.x] = fc1b[threadIdx.x];
    w2[threadIdx.x] = fc2W[threadIdx.x];
  }
  __syncthreads();
  int t = blockIdx.x * blockDim.x + threadIdx.x;
  if (t >= T) return;
  const float* hrow = top + (size_t)t * kH;
  float hv[kH];
#pragma unroll
  for (int k = 0; k < kH; k += 4) {
    const float4 h4 = *reinterpret_cast<const float4*>(hrow + k);
    hv[k] = h4.x; hv[k + 1] = h4.y; hv[k + 2] = h4.z; hv[k + 3] = h4.w;
  }
  float o = fc2b[0];
#pragma unroll
  for (int mth = 0; mth < 32; ++mth) {
    float a = b1[mth];
#pragma unroll
    for (int k = 0; k < kH; ++k) a = fmaf(hv[k], w1[mth * kH + k], a);
    a = fmaxf(a, 0.0f);
    o = fmaf(a, w2[mth], o);
  }
  out[t] = o;
}

extern "C" void kernel_launch(void* const* d_in, const int* in_sizes, int n_in,
                              void* d_out, int out_size, void* d_ws, size_t ws_size,
                              hipStream_t stream) {
  const float* batch = (const float*)d_in[0];
  const float* Wih0  = (const float*)d_in[1];
  const float* Whh0  = (const float*)d_in[2];
  const float* bih0  = (const float*)d_in[3];
  const float* bhh0  = (const float*)d_in[4];
  const float* Wih   = (const float*)d_in[5];
  const float* Whh   = (const float*)d_in[6];
  const float* bih   = (const float*)d_in[7];
  const float* bhh   = (const float*)d_in[8];
  const float* aW    = (const float*)d_in[9];
  const float* ab    = (const float*)d_in[10];
  const float* av    = (const float*)d_in[11];
  const float* avb   = (const float*)d_in[12];
  const float* fc1W  = (const float*)d_in[13];
  const float* fc1b  = (const float*)d_in[14];
  const float* fc2W  = (const float*)d_in[15];
  const float* fc2b  = (const float*)d_in[16];
  float* out = (float*)d_out;

  const int T = in_sizes[0] / kF;  // 131072

  // workspace layout: gi0 [T*48 f32] | top [T*16 f32]
  float* gi0 = (float*)d_ws;
  float* top = gi0 + (size_t)T * kG;

  const int blocks = (T + 255) / 256;
  gi0_kernel<<<blocks, 256, 0, stream>>>(batch, Wih0, bih0, gi0, T);
  seq_kernel<<<1, 64, 0, stream>>>(Whh0, bhh0, Wih, Whh, bih, bhh,
                                   aW, ab, av, avb, gi0, top, T);
  head_kernel<<<blocks, 256, 0, stream>>>(top, fc1W, fc1b, fc2W, fc2b, out, T);
}